// Round 15
// baseline (4120.044 us; speedup 1.0000x reference)
//
#include <hip/hip_runtime.h>

// ---------------- CSR build ----------------

__global__ void degree_kernel(const int* __restrict__ ei, int* __restrict__ deg, int E) {
    int e = blockIdx.x * blockDim.x + threadIdx.x;
    if (e < E) {
        int dst = ei[E + e];
        atomicAdd(&deg[dst], 1);
    }
}

// ---- hierarchical exclusive scan of deg -> offs (+ invd) ----

__global__ __launch_bounds__(512) void block_sum_kernel(
    const int* __restrict__ deg, int* __restrict__ bsum, int n)
{
    __shared__ int s[512];
    int i = blockIdx.x * 512 + threadIdx.x;
    s[threadIdx.x] = (i < n) ? deg[i] : 0;
    __syncthreads();
#pragma unroll
    for (int off = 256; off > 0; off >>= 1) {
        if (threadIdx.x < off) s[threadIdx.x] += s[threadIdx.x + off];
        __syncthreads();
    }
    if (threadIdx.x == 0) bsum[blockIdx.x] = s[0];
}

__global__ __launch_bounds__(1024) void bsum_scan_kernel(int* __restrict__ bsum, int nb) {
    __shared__ int s[1024];
    int t = threadIdx.x;
    s[t] = (t < nb) ? bsum[t] : 0;
    __syncthreads();
    for (int off = 1; off < 1024; off <<= 1) {
        int v = 0;
        if (t >= off) v = s[t - off];
        __syncthreads();
        if (t >= off) s[t] += v;
        __syncthreads();
    }
    if (t < nb) bsum[t] = (t == 0) ? 0 : s[t - 1];
}

__global__ __launch_bounds__(512) void scan_write_kernel(
    const int* __restrict__ deg, const int* __restrict__ bsum,
    int* __restrict__ offs, float* __restrict__ invd, int n, int E)
{
    __shared__ int s[512];
    int t = threadIdx.x;
    int i = blockIdx.x * 512 + t;
    int d = (i < n) ? deg[i] : 0;
    s[t] = d;
    __syncthreads();
    for (int off = 1; off < 512; off <<= 1) {
        int v = 0;
        if (t >= off) v = s[t - off];
        __syncthreads();
        if (t >= off) s[t] += v;
        __syncthreads();
    }
    if (i < n) {
        offs[i] = bsum[blockIdx.x] + s[t] - d;   // exclusive prefix
        invd[i] = 1.0f / (float)(d > 0 ? d : 1);
    }
    if (blockIdx.x == 0 && t == 0) offs[n] = E;
}

__global__ void fill_kernel(const int* __restrict__ ei, const int* __restrict__ offs,
                            int* __restrict__ cursor, int* __restrict__ csr, int E) {
    int e = blockIdx.x * blockDim.x + threadIdx.x;
    if (e < E) {
        int src = ei[e];
        int dst = ei[E + e];
        int pos = atomicAdd(&cursor[dst], 1);
        csr[offs[dst] + pos] = src;
    }
}

// ---------------- mean aggregation: one wave per node, float4 gather ----------------

template <int D>
__global__ __launch_bounds__(256) void aggregate_kernel(
    const float* __restrict__ h, const int* __restrict__ offs,
    const int* __restrict__ csr, const float* __restrict__ invd,
    float* __restrict__ mean, int nN)
{
    constexpr int LPR = D / 4;      // lanes per row (32 for D=128, 16 for D=64)
    constexpr int G = 64 / LPR;     // neighbor groups per wave (2 or 4)
    int wid = blockIdx.x * 4 + (threadIdx.x >> 6);
    int lane = threadIdx.x & 63;
    if (wid >= nN) return;
    int o0 = offs[wid], o1 = offs[wid + 1];
    const int p = lane / LPR;
    const int col = (lane % LPR) * 4;

    float4 a0 = make_float4(0.f, 0.f, 0.f, 0.f);
    float4 a1 = make_float4(0.f, 0.f, 0.f, 0.f);
    int j = o0;
    for (; j + 2 * G <= o1; j += 2 * G) {
        int s0 = csr[j + p];
        int s1 = csr[j + G + p];
        float4 v0 = *(const float4*)(h + (size_t)s0 * D + col);
        float4 v1 = *(const float4*)(h + (size_t)s1 * D + col);
        a0.x += v0.x; a0.y += v0.y; a0.z += v0.z; a0.w += v0.w;
        a1.x += v1.x; a1.y += v1.y; a1.z += v1.z; a1.w += v1.w;
    }
    if (j + G <= o1) {
        int s0 = csr[j + p];
        float4 v0 = *(const float4*)(h + (size_t)s0 * D + col);
        a0.x += v0.x; a0.y += v0.y; a0.z += v0.z; a0.w += v0.w;
        j += G;
    }
    if (j < o1 && p < o1 - j) {      // partial group (0..G-1 neighbors left)
        int s1 = csr[j + p];
        float4 v1 = *(const float4*)(h + (size_t)s1 * D + col);
        a1.x += v1.x; a1.y += v1.y; a1.z += v1.z; a1.w += v1.w;
    }
    a0.x += a1.x; a0.y += a1.y; a0.z += a1.z; a0.w += a1.w;

#pragma unroll
    for (int m = LPR; m < 64; m <<= 1) {
        a0.x += __shfl_xor(a0.x, m);
        a0.y += __shfl_xor(a0.y, m);
        a0.z += __shfl_xor(a0.z, m);
        a0.w += __shfl_xor(a0.w, m);
    }

    if (lane < LPR) {
        float iv = invd[wid];
        float4 r = make_float4(a0.x * iv, a0.y * iv, a0.z * iv, a0.w * iv);
        *(float4*)(mean + (size_t)wid * D + col) = r;
    }
}

// ---------------- fused dual GEMM + bias + ReLU, W in LDS, A reg-pipelined ----
// Round-14: clean (VGPR 56, traffic algorithmic) but each kk0 iteration exposes
// one A-row L2/L3 latency (~600 cyc) -> 144us vs 42 ideal. This round: software-
// pipeline ONLY the A loads (X/Y named buffers, prefetch distance = 1 chunk).
// W stays in LDS so the extra buffer is +32 VGPR (~100 total < 128 budget).

__device__ inline void fma4(float4& a, float s, const float4& w) {
    a.x = fmaf(s, w.x, a.x);
    a.y = fmaf(s, w.y, a.y);
    a.z = fmaf(s, w.z, a.z);
    a.w = fmaf(s, w.w, a.w);
}

template <int K, int M, int R, int NS>
__global__ __launch_bounds__(512, 4) void gemm_relu_ldsw(
    const float* __restrict__ A1, const float* __restrict__ A2,
    const float* __restrict__ wl, const float* __restrict__ wr,
    const float* __restrict__ bias, float* __restrict__ out, int nN)
{
    constexpr int KQ = K / NS;            // k-slice staged at a time
    constexpr int TXc = M / 4;            // threads per row-group
    constexpr int GROUPS = 512 / TXc;
    constexpr int ROWS = GROUPS * R;      // rows per block
    constexpr int F4 = KQ * M / 4;        // float4s per matrix slice

    __shared__ float ws[2 * KQ * M];      // [0..) = wl slice, [KQ*M..) = wr slice

    const int tid = threadIdx.x;
    const int cq = (tid % TXc) * 4;
    const int g = tid / TXc;
    const int nbase = blockIdx.x * ROWS;
    const int n0 = nbase + g * R;
    const bool full = (nbase + ROWS <= nN);

    const float4 bv = *(const float4*)(bias + cq);
    float4 acc[R];
#pragma unroll
    for (int rr = 0; rr < R; rr++) acc[rr] = bv;

#pragma unroll
    for (int s = 0; s < NS; s++) {
        __syncthreads();                   // previous slice's compute done
        const float4* wlg = (const float4*)(wl + (size_t)s * KQ * M);
        const float4* wrg = (const float4*)(wr + (size_t)s * KQ * M);
        float4* s0 = (float4*)ws;
        float4* s1 = (float4*)(ws + KQ * M);
        for (int i = tid; i < F4; i += 512) {
            s0[i] = wlg[i];
            s1[i] = wrg[i];
        }
        __syncthreads();

        const int kbase = s * KQ;
        if (full) {
            const float* __restrict__ a1p = A1 + (size_t)n0 * K + kbase;
            const float* __restrict__ a2p = A2 + (size_t)n0 * K + kbase;

            float4 a1X[R], a2X[R], a1Y[R], a2Y[R];

#define LOADA(B1, B2, kk)                                                 \
            _Pragma("unroll") for (int rr = 0; rr < R; rr++) {            \
                B1[rr] = *(const float4*)(a1p + (size_t)rr * K + (kk));   \
                B2[rr] = *(const float4*)(a2p + (size_t)rr * K + (kk));   \
            }                                                             \
            __builtin_amdgcn_sched_barrier(0);

#define DOFMA(B1, B2, kk)                                                 \
            {                                                             \
                float4 wlv[4], wrv[4];                                    \
                _Pragma("unroll") for (int j = 0; j < 4; j++) {           \
                    wlv[j] = *(const float4*)(&ws[((kk) + j) * M + cq]);  \
                    wrv[j] = *(const float4*)(&ws[KQ * M + ((kk) + j) * M + cq]); \
                }                                                         \
                _Pragma("unroll") for (int rr = 0; rr < R; rr++) {        \
                    fma4(acc[rr], B1[rr].x, wlv[0]);                      \
                    fma4(acc[rr], B1[rr].y, wlv[1]);                      \
                    fma4(acc[rr], B1[rr].z, wlv[2]);                      \
                    fma4(acc[rr], B1[rr].w, wlv[3]);                      \
                    fma4(acc[rr], B2[rr].x, wrv[0]);                      \
                    fma4(acc[rr], B2[rr].y, wrv[1]);                      \
                    fma4(acc[rr], B2[rr].z, wrv[2]);                      \
                    fma4(acc[rr], B2[rr].w, wrv[3]);                      \
                }                                                         \
            }

            LOADA(a1X, a2X, 0)
#pragma unroll
            for (int kk0 = 0; kk0 < KQ; kk0 += 8) {
                LOADA(a1Y, a2Y, kk0 + 4)
                DOFMA(a1X, a2X, kk0)
                if (kk0 + 8 < KQ) {
                    LOADA(a1X, a2X, kk0 + 8)
                }
                DOFMA(a1Y, a2Y, kk0 + 4)
            }
#undef LOADA
#undef DOFMA
        } else {
            for (int kk0 = 0; kk0 < KQ; kk0 += 4) {
                float4 wlv[4], wrv[4];
#pragma unroll
                for (int j = 0; j < 4; j++) {
                    wlv[j] = *(const float4*)(&ws[(kk0 + j) * M + cq]);
                    wrv[j] = *(const float4*)(&ws[KQ * M + (kk0 + j) * M + cq]);
                }
#pragma unroll
                for (int rr = 0; rr < R; rr++) {
                    int n = n0 + rr;
                    if (n < nN) {
                        float4 a1 = *(const float4*)(A1 + (size_t)n * K + kbase + kk0);
                        float4 a2 = *(const float4*)(A2 + (size_t)n * K + kbase + kk0);
                        fma4(acc[rr], a1.x, wlv[0]);
                        fma4(acc[rr], a1.y, wlv[1]);
                        fma4(acc[rr], a1.z, wlv[2]);
                        fma4(acc[rr], a1.w, wlv[3]);
                        fma4(acc[rr], a2.x, wrv[0]);
                        fma4(acc[rr], a2.y, wrv[1]);
                        fma4(acc[rr], a2.z, wrv[2]);
                        fma4(acc[rr], a2.w, wrv[3]);
                    }
                }
            }
        }
    }

#pragma unroll
    for (int rr = 0; rr < R; rr++) {
        int n = n0 + rr;
        if (n < nN) {
            float4 v = acc[rr];
            v.x = fmaxf(v.x, 0.f); v.y = fmaxf(v.y, 0.f);
            v.z = fmaxf(v.z, 0.f); v.w = fmaxf(v.w, 0.f);
            *(float4*)(out + (size_t)n * M + cq) = v;
        }
    }
}

// ---------------- classifier: [N,32] @ [32,2] + bc ----------------

__global__ void classifier_kernel(const float* __restrict__ h,
                                  const float* __restrict__ wc,
                                  const float* __restrict__ bc,
                                  float* __restrict__ out, int nN) {
    int n = blockIdx.x * blockDim.x + threadIdx.x;
    if (n >= nN) return;
    float a0 = bc[0], a1 = bc[1];
    const float* row = h + (size_t)n * 32;
#pragma unroll
    for (int k = 0; k < 32; k++) {
        float v = row[k];
        a0 = fmaf(v, wc[k * 2 + 0], a0);
        a1 = fmaf(v, wc[k * 2 + 1], a1);
    }
    out[n * 2 + 0] = a0;
    out[n * 2 + 1] = a1;
}

// ---------------- launch ----------------

extern "C" void kernel_launch(void* const* d_in, const int* in_sizes, int n_in,
                              void* d_out, int out_size, void* d_ws, size_t ws_size,
                              hipStream_t stream) {
    const float* x   = (const float*)d_in[0];
    const int*   ei  = (const int*)d_in[1];   // [2,E] int32
    const float* w1l = (const float*)d_in[2];
    const float* b1l = (const float*)d_in[3];
    const float* w1r = (const float*)d_in[4];
    const float* w2l = (const float*)d_in[5];
    const float* b2l = (const float*)d_in[6];
    const float* w2r = (const float*)d_in[7];
    const float* w3l = (const float*)d_in[8];
    const float* b3l = (const float*)d_in[9];
    const float* w3r = (const float*)d_in[10];
    const float* wc  = (const float*)d_in[11];
    const float* bc  = (const float*)d_in[12];
    float* out = (float*)d_out;

    const int N = in_sizes[0] / 128;
    const int E = in_sizes[1] / 2;
    const int NB = (N + 511) / 512;           // scan blocks (<=1024)

    char* p = (char*)d_ws;
    auto alloc = [&](size_t bytes) {
        char* r = p;
        p += (bytes + 511) & ~(size_t)511;
        return r;
    };
    int*   deg    = (int*)  alloc((size_t)N * 4);
    int*   offs   = (int*)  alloc(((size_t)N + 1) * 4);
    int*   cursor = (int*)  alloc((size_t)N * 4);
    float* invd   = (float*)alloc((size_t)N * 4);
    int*   bsum   = (int*)  alloc((size_t)NB * 4);
    int*   csr    = (int*)  alloc((size_t)E * 4);
    float* mean   = (float*)alloc((size_t)N * 128 * 4);
    float* h1     = (float*)alloc((size_t)N * 128 * 4);
    float* h2     = (float*)alloc((size_t)N * 64 * 4);
    float* h3     = (float*)alloc((size_t)N * 32 * 4);

    hipMemsetAsync(deg, 0, (size_t)N * 4, stream);
    hipMemsetAsync(cursor, 0, (size_t)N * 4, stream);

    int eb = (E + 255) / 256;
    degree_kernel<<<eb, 256, 0, stream>>>(ei, deg, E);
    block_sum_kernel<<<NB, 512, 0, stream>>>(deg, bsum, N);
    bsum_scan_kernel<<<1, 1024, 0, stream>>>(bsum, NB);
    scan_write_kernel<<<NB, 512, 0, stream>>>(deg, bsum, offs, invd, N, E);
    fill_kernel<<<eb, 256, 0, stream>>>(ei, offs, cursor, csr, E);

    int ab = (N + 3) / 4;

    // rows per block = (512/(M/4)) * R = 8192/M (R=4)
    int g1 = (N + 8192 / 128 - 1) / (8192 / 128);   // 64 rows/blk  -> 1563
    int g2 = (N + 8192 / 64  - 1) / (8192 / 64);    // 128 rows/blk -> 782
    int g3 = (N + 8192 / 32  - 1) / (8192 / 32);    // 256 rows/blk -> 391

    aggregate_kernel<128><<<ab, 256, 0, stream>>>(x, offs, csr, invd, mean, N);
    gemm_relu_ldsw<128, 128, 4, 4><<<g1, 512, 0, stream>>>(mean, x, w1l, w1r, b1l, h1, N);

    aggregate_kernel<128><<<ab, 256, 0, stream>>>(h1, offs, csr, invd, mean, N);
    gemm_relu_ldsw<128, 64, 4, 4><<<g2, 512, 0, stream>>>(mean, h1, w2l, w2r, b2l, h2, N);

    aggregate_kernel<64><<<ab, 256, 0, stream>>>(h2, offs, csr, invd, mean, N);
    gemm_relu_ldsw<64, 32, 4, 2><<<g3, 512, 0, stream>>>(mean, h2, w3l, w3r, b3l, h3, N);

    classifier_kernel<<<(N + 255) / 256, 256, 0, stream>>>(h3, wc, bc, out, N);
}

// Round 16
// 709.894 us; speedup vs baseline: 5.8037x; 5.8037x over previous
//
#include <hip/hip_runtime.h>

// ---------------- CSR build ----------------

__global__ void degree_kernel(const int* __restrict__ ei, int* __restrict__ deg, int E) {
    int e = blockIdx.x * blockDim.x + threadIdx.x;
    if (e < E) {
        int dst = ei[E + e];
        atomicAdd(&deg[dst], 1);
    }
}

// ---- hierarchical exclusive scan of deg -> offs (+ invd) ----

__global__ __launch_bounds__(512) void block_sum_kernel(
    const int* __restrict__ deg, int* __restrict__ bsum, int n)
{
    __shared__ int s[512];
    int i = blockIdx.x * 512 + threadIdx.x;
    s[threadIdx.x] = (i < n) ? deg[i] : 0;
    __syncthreads();
#pragma unroll
    for (int off = 256; off > 0; off >>= 1) {
        if (threadIdx.x < off) s[threadIdx.x] += s[threadIdx.x + off];
        __syncthreads();
    }
    if (threadIdx.x == 0) bsum[blockIdx.x] = s[0];
}

__global__ __launch_bounds__(1024) void bsum_scan_kernel(int* __restrict__ bsum, int nb) {
    __shared__ int s[1024];
    int t = threadIdx.x;
    s[t] = (t < nb) ? bsum[t] : 0;
    __syncthreads();
    for (int off = 1; off < 1024; off <<= 1) {
        int v = 0;
        if (t >= off) v = s[t - off];
        __syncthreads();
        if (t >= off) s[t] += v;
        __syncthreads();
    }
    if (t < nb) bsum[t] = (t == 0) ? 0 : s[t - 1];
}

__global__ __launch_bounds__(512) void scan_write_kernel(
    const int* __restrict__ deg, const int* __restrict__ bsum,
    int* __restrict__ offs, float* __restrict__ invd, int n, int E)
{
    __shared__ int s[512];
    int t = threadIdx.x;
    int i = blockIdx.x * 512 + t;
    int d = (i < n) ? deg[i] : 0;
    s[t] = d;
    __syncthreads();
    for (int off = 1; off < 512; off <<= 1) {
        int v = 0;
        if (t >= off) v = s[t - off];
        __syncthreads();
        if (t >= off) s[t] += v;
        __syncthreads();
    }
    if (i < n) {
        offs[i] = bsum[blockIdx.x] + s[t] - d;   // exclusive prefix
        invd[i] = 1.0f / (float)(d > 0 ? d : 1);
    }
    if (blockIdx.x == 0 && t == 0) offs[n] = E;
}

__global__ void fill_kernel(const int* __restrict__ ei, const int* __restrict__ offs,
                            int* __restrict__ cursor, int* __restrict__ csr, int E) {
    int e = blockIdx.x * blockDim.x + threadIdx.x;
    if (e < E) {
        int src = ei[e];
        int dst = ei[E + e];
        int pos = atomicAdd(&cursor[dst], 1);
        csr[offs[dst] + pos] = src;
    }
}

// ---------------- mean aggregation: one wave per node, float4 gather ----------------
// Round-16: widen from 2 to 4 independent accumulator chains (4 neighbor rows
// in flight per iteration) to cover gather latency with ILP.

template <int D>
__global__ __launch_bounds__(256) void aggregate_kernel(
    const float* __restrict__ h, const int* __restrict__ offs,
    const int* __restrict__ csr, const float* __restrict__ invd,
    float* __restrict__ mean, int nN)
{
    constexpr int LPR = D / 4;      // lanes per row (32 for D=128, 16 for D=64)
    constexpr int G = 64 / LPR;     // neighbor groups per wave (2 or 4)
    int wid = blockIdx.x * 4 + (threadIdx.x >> 6);
    int lane = threadIdx.x & 63;
    if (wid >= nN) return;
    int o0 = offs[wid], o1 = offs[wid + 1];
    const int p = lane / LPR;
    const int col = (lane % LPR) * 4;

    float4 a0 = make_float4(0.f, 0.f, 0.f, 0.f);
    float4 a1 = make_float4(0.f, 0.f, 0.f, 0.f);
    float4 a2 = make_float4(0.f, 0.f, 0.f, 0.f);
    float4 a3 = make_float4(0.f, 0.f, 0.f, 0.f);
    int j = o0;
    for (; j + 4 * G <= o1; j += 4 * G) {
        int s0 = csr[j + p];
        int s1 = csr[j + G + p];
        int s2 = csr[j + 2 * G + p];
        int s3 = csr[j + 3 * G + p];
        float4 v0 = *(const float4*)(h + (size_t)s0 * D + col);
        float4 v1 = *(const float4*)(h + (size_t)s1 * D + col);
        float4 v2 = *(const float4*)(h + (size_t)s2 * D + col);
        float4 v3 = *(const float4*)(h + (size_t)s3 * D + col);
        a0.x += v0.x; a0.y += v0.y; a0.z += v0.z; a0.w += v0.w;
        a1.x += v1.x; a1.y += v1.y; a1.z += v1.z; a1.w += v1.w;
        a2.x += v2.x; a2.y += v2.y; a2.z += v2.z; a2.w += v2.w;
        a3.x += v3.x; a3.y += v3.y; a3.z += v3.z; a3.w += v3.w;
    }
    for (; j + G <= o1; j += G) {
        int s0 = csr[j + p];
        float4 v0 = *(const float4*)(h + (size_t)s0 * D + col);
        a0.x += v0.x; a0.y += v0.y; a0.z += v0.z; a0.w += v0.w;
    }
    if (j < o1 && p < o1 - j) {      // partial group (0..G-1 neighbors left)
        int s1 = csr[j + p];
        float4 v1 = *(const float4*)(h + (size_t)s1 * D + col);
        a1.x += v1.x; a1.y += v1.y; a1.z += v1.z; a1.w += v1.w;
    }
    a0.x += a1.x + a2.x + a3.x;
    a0.y += a1.y + a2.y + a3.y;
    a0.z += a1.z + a2.z + a3.z;
    a0.w += a1.w + a2.w + a3.w;

#pragma unroll
    for (int m = LPR; m < 64; m <<= 1) {
        a0.x += __shfl_xor(a0.x, m);
        a0.y += __shfl_xor(a0.y, m);
        a0.z += __shfl_xor(a0.z, m);
        a0.w += __shfl_xor(a0.w, m);
    }

    if (lane < LPR) {
        float iv = invd[wid];
        float4 r = make_float4(a0.x * iv, a0.y * iv, a0.z * iv, a0.w * iv);
        *(float4*)(mean + (size_t)wid * D + col) = r;
    }
}

// ---------------- fused dual GEMM + bias + ReLU, W staged in LDS ----------------
// ROUND-14 FORM — DO NOT register-pipeline A (spilled in r11/r13/r15; null in
// r8/r9). W in LDS (NS k-slices), single-chunk A loads, launch_bounds(512,4).
// 144us/layer-1, VGPR 56, traffic algorithmic.

__device__ inline void fma4(float4& a, float s, const float4& w) {
    a.x = fmaf(s, w.x, a.x);
    a.y = fmaf(s, w.y, a.y);
    a.z = fmaf(s, w.z, a.z);
    a.w = fmaf(s, w.w, a.w);
}

template <int K, int M, int R, int NS>
__global__ __launch_bounds__(512, 4) void gemm_relu_ldsw(
    const float* __restrict__ A1, const float* __restrict__ A2,
    const float* __restrict__ wl, const float* __restrict__ wr,
    const float* __restrict__ bias, float* __restrict__ out, int nN)
{
    constexpr int KQ = K / NS;            // k-slice staged at a time
    constexpr int TXc = M / 4;            // threads per row-group
    constexpr int GROUPS = 512 / TXc;
    constexpr int ROWS = GROUPS * R;      // rows per block
    constexpr int F4 = KQ * M / 4;        // float4s per matrix slice

    __shared__ float ws[2 * KQ * M];      // [0..) = wl slice, [KQ*M..) = wr slice

    const int tid = threadIdx.x;
    const int cq = (tid % TXc) * 4;
    const int g = tid / TXc;
    const int nbase = blockIdx.x * ROWS;
    const int n0 = nbase + g * R;
    const bool full = (nbase + ROWS <= nN);

    const float4 bv = *(const float4*)(bias + cq);
    float4 acc[R];
#pragma unroll
    for (int rr = 0; rr < R; rr++) acc[rr] = bv;

#pragma unroll
    for (int s = 0; s < NS; s++) {
        __syncthreads();                   // previous slice's compute done
        const float4* wlg = (const float4*)(wl + (size_t)s * KQ * M);
        const float4* wrg = (const float4*)(wr + (size_t)s * KQ * M);
        float4* s0 = (float4*)ws;
        float4* s1 = (float4*)(ws + KQ * M);
        for (int i = tid; i < F4; i += 512) {
            s0[i] = wlg[i];
            s1[i] = wrg[i];
        }
        __syncthreads();

        const int kbase = s * KQ;
        if (full) {
            const float* __restrict__ a1p = A1 + (size_t)n0 * K + kbase;
            const float* __restrict__ a2p = A2 + (size_t)n0 * K + kbase;
            for (int kk0 = 0; kk0 < KQ; kk0 += 4) {
                float4 a1v[R], a2v[R];
#pragma unroll
                for (int rr = 0; rr < R; rr++) {
                    a1v[rr] = *(const float4*)(a1p + (size_t)rr * K + kk0);
                    a2v[rr] = *(const float4*)(a2p + (size_t)rr * K + kk0);
                }
                float4 wlv[4], wrv[4];
#pragma unroll
                for (int j = 0; j < 4; j++) {
                    wlv[j] = *(const float4*)(&ws[(kk0 + j) * M + cq]);
                    wrv[j] = *(const float4*)(&ws[KQ * M + (kk0 + j) * M + cq]);
                }
#pragma unroll
                for (int rr = 0; rr < R; rr++) {
                    fma4(acc[rr], a1v[rr].x, wlv[0]);
                    fma4(acc[rr], a1v[rr].y, wlv[1]);
                    fma4(acc[rr], a1v[rr].z, wlv[2]);
                    fma4(acc[rr], a1v[rr].w, wlv[3]);
                    fma4(acc[rr], a2v[rr].x, wrv[0]);
                    fma4(acc[rr], a2v[rr].y, wrv[1]);
                    fma4(acc[rr], a2v[rr].z, wrv[2]);
                    fma4(acc[rr], a2v[rr].w, wrv[3]);
                }
            }
        } else {
            for (int kk0 = 0; kk0 < KQ; kk0 += 4) {
                float4 wlv[4], wrv[4];
#pragma unroll
                for (int j = 0; j < 4; j++) {
                    wlv[j] = *(const float4*)(&ws[(kk0 + j) * M + cq]);
                    wrv[j] = *(const float4*)(&ws[KQ * M + (kk0 + j) * M + cq]);
                }
#pragma unroll
                for (int rr = 0; rr < R; rr++) {
                    int n = n0 + rr;
                    if (n < nN) {
                        float4 a1 = *(const float4*)(A1 + (size_t)n * K + kbase + kk0);
                        float4 a2 = *(const float4*)(A2 + (size_t)n * K + kbase + kk0);
                        fma4(acc[rr], a1.x, wlv[0]);
                        fma4(acc[rr], a1.y, wlv[1]);
                        fma4(acc[rr], a1.z, wlv[2]);
                        fma4(acc[rr], a1.w, wlv[3]);
                        fma4(acc[rr], a2.x, wrv[0]);
                        fma4(acc[rr], a2.y, wrv[1]);
                        fma4(acc[rr], a2.z, wrv[2]);
                        fma4(acc[rr], a2.w, wrv[3]);
                    }
                }
            }
        }
    }

#pragma unroll
    for (int rr = 0; rr < R; rr++) {
        int n = n0 + rr;
        if (n < nN) {
            float4 v = acc[rr];
            v.x = fmaxf(v.x, 0.f); v.y = fmaxf(v.y, 0.f);
            v.z = fmaxf(v.z, 0.f); v.w = fmaxf(v.w, 0.f);
            *(float4*)(out + (size_t)n * M + cq) = v;
        }
    }
}

// ---------------- classifier: [N,32] @ [32,2] + bc ----------------

__global__ void classifier_kernel(const float* __restrict__ h,
                                  const float* __restrict__ wc,
                                  const float* __restrict__ bc,
                                  float* __restrict__ out, int nN) {
    int n = blockIdx.x * blockDim.x + threadIdx.x;
    if (n >= nN) return;
    float a0 = bc[0], a1 = bc[1];
    const float* row = h + (size_t)n * 32;
#pragma unroll
    for (int k = 0; k < 32; k++) {
        float v = row[k];
        a0 = fmaf(v, wc[k * 2 + 0], a0);
        a1 = fmaf(v, wc[k * 2 + 1], a1);
    }
    out[n * 2 + 0] = a0;
    out[n * 2 + 1] = a1;
}

// ---------------- launch ----------------

extern "C" void kernel_launch(void* const* d_in, const int* in_sizes, int n_in,
                              void* d_out, int out_size, void* d_ws, size_t ws_size,
                              hipStream_t stream) {
    const float* x   = (const float*)d_in[0];
    const int*   ei  = (const int*)d_in[1];   // [2,E] int32
    const float* w1l = (const float*)d_in[2];
    const float* b1l = (const float*)d_in[3];
    const float* w1r = (const float*)d_in[4];
    const float* w2l = (const float*)d_in[5];
    const float* b2l = (const float*)d_in[6];
    const float* w2r = (const float*)d_in[7];
    const float* w3l = (const float*)d_in[8];
    const float* b3l = (const float*)d_in[9];
    const float* w3r = (const float*)d_in[10];
    const float* wc  = (const float*)d_in[11];
    const float* bc  = (const float*)d_in[12];
    float* out = (float*)d_out;

    const int N = in_sizes[0] / 128;
    const int E = in_sizes[1] / 2;
    const int NB = (N + 511) / 512;           // scan blocks (<=1024)

    char* p = (char*)d_ws;
    auto alloc = [&](size_t bytes) {
        char* r = p;
        p += (bytes + 511) & ~(size_t)511;
        return r;
    };
    int*   deg    = (int*)  alloc((size_t)N * 4);
    int*   offs   = (int*)  alloc(((size_t)N + 1) * 4);
    int*   cursor = (int*)  alloc((size_t)N * 4);
    float* invd   = (float*)alloc((size_t)N * 4);
    int*   bsum   = (int*)  alloc((size_t)NB * 4);
    int*   csr    = (int*)  alloc((size_t)E * 4);
    float* mean   = (float*)alloc((size_t)N * 128 * 4);
    float* h1     = (float*)alloc((size_t)N * 128 * 4);
    float* h2     = (float*)alloc((size_t)N * 64 * 4);
    float* h3     = (float*)alloc((size_t)N * 32 * 4);

    hipMemsetAsync(deg, 0, (size_t)N * 4, stream);
    hipMemsetAsync(cursor, 0, (size_t)N * 4, stream);

    int eb = (E + 255) / 256;
    degree_kernel<<<eb, 256, 0, stream>>>(ei, deg, E);
    block_sum_kernel<<<NB, 512, 0, stream>>>(deg, bsum, N);
    bsum_scan_kernel<<<1, 1024, 0, stream>>>(bsum, NB);
    scan_write_kernel<<<NB, 512, 0, stream>>>(deg, bsum, offs, invd, N, E);
    fill_kernel<<<eb, 256, 0, stream>>>(ei, offs, cursor, csr, E);

    int ab = (N + 3) / 4;

    // rows per block = (512/(M/4)) * R = 8192/M (R=4)
    int g1 = (N + 8192 / 128 - 1) / (8192 / 128);   // 64 rows/blk  -> 1563
    int g2 = (N + 8192 / 64  - 1) / (8192 / 64);    // 128 rows/blk -> 782
    int g3 = (N + 8192 / 32  - 1) / (8192 / 32);    // 256 rows/blk -> 391

    aggregate_kernel<128><<<ab, 256, 0, stream>>>(x, offs, csr, invd, mean, N);
    gemm_relu_ldsw<128, 128, 4, 4><<<g1, 512, 0, stream>>>(mean, x, w1l, w1r, b1l, h1, N);

    aggregate_kernel<128><<<ab, 256, 0, stream>>>(h1, offs, csr, invd, mean, N);
    gemm_relu_ldsw<128, 64, 4, 4><<<g2, 512, 0, stream>>>(mean, h1, w2l, w2r, b2l, h2, N);

    aggregate_kernel<64><<<ab, 256, 0, stream>>>(h2, offs, csr, invd, mean, N);
    gemm_relu_ldsw<64, 32, 4, 2><<<g3, 512, 0, stream>>>(mean, h2, w3l, w3r, b3l, h3, N);

    classifier_kernel<<<(N + 255) / 256, 256, 0, stream>>>(h3, wc, bc, out, N);
}

// Round 18
// 605.929 us; speedup vs baseline: 6.7995x; 1.1716x over previous
//
#include <hip/hip_runtime.h>

// ---------------- CSR build ----------------

__global__ void degree_kernel(const int* __restrict__ ei, int* __restrict__ deg, int E) {
    int e = blockIdx.x * blockDim.x + threadIdx.x;
    if (e < E) {
        int dst = ei[E + e];
        atomicAdd(&deg[dst], 1);
    }
}

// ---- hierarchical exclusive scan of deg -> offs (+ invd) ----

__global__ __launch_bounds__(512) void block_sum_kernel(
    const int* __restrict__ deg, int* __restrict__ bsum, int n)
{
    __shared__ int s[512];
    int i = blockIdx.x * 512 + threadIdx.x;
    s[threadIdx.x] = (i < n) ? deg[i] : 0;
    __syncthreads();
#pragma unroll
    for (int off = 256; off > 0; off >>= 1) {
        if (threadIdx.x < off) s[threadIdx.x] += s[threadIdx.x + off];
        __syncthreads();
    }
    if (threadIdx.x == 0) bsum[blockIdx.x] = s[0];
}

__global__ __launch_bounds__(1024) void bsum_scan_kernel(int* __restrict__ bsum, int nb) {
    __shared__ int s[1024];
    int t = threadIdx.x;
    s[t] = (t < nb) ? bsum[t] : 0;
    __syncthreads();
    for (int off = 1; off < 1024; off <<= 1) {
        int v = 0;
        if (t >= off) v = s[t - off];
        __syncthreads();
        if (t >= off) s[t] += v;
        __syncthreads();
    }
    if (t < nb) bsum[t] = (t == 0) ? 0 : s[t - 1];
}

__global__ __launch_bounds__(512) void scan_write_kernel(
    const int* __restrict__ deg, const int* __restrict__ bsum,
    int* __restrict__ offs, float* __restrict__ invd, int n, int E)
{
    __shared__ int s[512];
    int t = threadIdx.x;
    int i = blockIdx.x * 512 + t;
    int d = (i < n) ? deg[i] : 0;
    s[t] = d;
    __syncthreads();
    for (int off = 1; off < 512; off <<= 1) {
        int v = 0;
        if (t >= off) v = s[t - off];
        __syncthreads();
        if (t >= off) s[t] += v;
        __syncthreads();
    }
    if (i < n) {
        offs[i] = bsum[blockIdx.x] + s[t] - d;   // exclusive prefix
        invd[i] = 1.0f / (float)(d > 0 ? d : 1);
    }
    if (blockIdx.x == 0 && t == 0) offs[n] = E;
}

__global__ void fill_kernel(const int* __restrict__ ei, const int* __restrict__ offs,
                            int* __restrict__ cursor, int* __restrict__ csr, int E) {
    int e = blockIdx.x * blockDim.x + threadIdx.x;
    if (e < E) {
        int src = ei[e];
        int dst = ei[E + e];
        int pos = atomicAdd(&cursor[dst], 1);
        csr[offs[dst] + pos] = src;
    }
}

// ---------------- fp32 -> bf16 conversion (RNE) ----------------

__device__ inline unsigned short f2bf(float f) {
    unsigned int u = __float_as_uint(f);
    return (unsigned short)((u + 0x7fffu + ((u >> 16) & 1u)) >> 16);
}

__global__ void f32_to_bf16_kernel(const float* __restrict__ in,
                                   unsigned short* __restrict__ out, int n4) {
    int i = blockIdx.x * blockDim.x + threadIdx.x;
    if (i < n4) {
        float4 v = *(const float4*)(in + (size_t)i * 4);
        ushort4 o;
        o.x = f2bf(v.x); o.y = f2bf(v.y); o.z = f2bf(v.z); o.w = f2bf(v.w);
        *(ushort4*)(out + (size_t)i * 4) = o;
    }
}

// ---------------- mean aggregation over bf16 rows (fp32 accumulate) ----------
// Round-17: gather input stored as bf16 -> 256B/row instead of 512B, halving
// the 819MB scattered-gather traffic per d=128 layer. Accumulate + mean fp32.

__device__ inline void addbf8(float* a, uint4 v) {
    a[0] += __uint_as_float(v.x << 16);
    a[1] += __uint_as_float(v.x & 0xffff0000u);
    a[2] += __uint_as_float(v.y << 16);
    a[3] += __uint_as_float(v.y & 0xffff0000u);
    a[4] += __uint_as_float(v.z << 16);
    a[5] += __uint_as_float(v.z & 0xffff0000u);
    a[6] += __uint_as_float(v.w << 16);
    a[7] += __uint_as_float(v.w & 0xffff0000u);
}

template <int D>
__global__ __launch_bounds__(256) void aggregate_bf16_kernel(
    const unsigned short* __restrict__ hb, const int* __restrict__ offs,
    const int* __restrict__ csr, const float* __restrict__ invd,
    float* __restrict__ mean, int nN)
{
    constexpr int LPR = D / 8;      // lanes per row (16 for D=128, 8 for D=64)
    constexpr int G = 64 / LPR;     // neighbor groups per wave (4 or 8)
    int wid = blockIdx.x * 4 + (threadIdx.x >> 6);
    int lane = threadIdx.x & 63;
    if (wid >= nN) return;
    int o0 = offs[wid], o1 = offs[wid + 1];
    const int p = lane / LPR;
    const int col = (lane % LPR) * 8;

    float a0[8] = {0.f, 0.f, 0.f, 0.f, 0.f, 0.f, 0.f, 0.f};
    float a1[8] = {0.f, 0.f, 0.f, 0.f, 0.f, 0.f, 0.f, 0.f};
    int j = o0;
    for (; j + 2 * G <= o1; j += 2 * G) {
        int s0 = csr[j + p];
        int s1 = csr[j + G + p];
        uint4 v0 = *(const uint4*)(hb + (size_t)s0 * D + col);
        uint4 v1 = *(const uint4*)(hb + (size_t)s1 * D + col);
        addbf8(a0, v0);
        addbf8(a1, v1);
    }
    if (j + G <= o1) {
        int s0 = csr[j + p];
        uint4 v0 = *(const uint4*)(hb + (size_t)s0 * D + col);
        addbf8(a0, v0);
        j += G;
    }
    if (j < o1 && p < o1 - j) {      // partial group
        int s1 = csr[j + p];
        uint4 v1 = *(const uint4*)(hb + (size_t)s1 * D + col);
        addbf8(a1, v1);
    }
#pragma unroll
    for (int q = 0; q < 8; q++) a0[q] += a1[q];

#pragma unroll
    for (int m = LPR; m < 64; m <<= 1) {
#pragma unroll
        for (int q = 0; q < 8; q++) a0[q] += __shfl_xor(a0[q], m);
    }

    if (lane < LPR) {
        float iv = invd[wid];
        float4 r0 = make_float4(a0[0] * iv, a0[1] * iv, a0[2] * iv, a0[3] * iv);
        float4 r1 = make_float4(a0[4] * iv, a0[5] * iv, a0[6] * iv, a0[7] * iv);
        float* dst = mean + (size_t)wid * D + col;
        *(float4*)(dst) = r0;
        *(float4*)(dst + 4) = r1;
    }
}

// ---------------- fused dual GEMM + bias + ReLU, W staged in LDS ----------------
// ROUND-14 FORM — DO NOT register-pipeline A (spilled in r11/r13/r15; null in
// r8/r9). W in LDS (NS k-slices), single-chunk A loads, launch_bounds(512,4).
// 144us/layer-1, VGPR 56, traffic algorithmic. Epilogue optionally also writes
// a bf16 copy of the output (gather input for the next layer's aggregation).

__device__ inline void fma4(float4& a, float s, const float4& w) {
    a.x = fmaf(s, w.x, a.x);
    a.y = fmaf(s, w.y, a.y);
    a.z = fmaf(s, w.z, a.z);
    a.w = fmaf(s, w.w, a.w);
}

template <int K, int M, int R, int NS>
__global__ __launch_bounds__(512, 4) void gemm_relu_ldsw(
    const float* __restrict__ A1, const float* __restrict__ A2,
    const float* __restrict__ wl, const float* __restrict__ wr,
    const float* __restrict__ bias, float* __restrict__ out,
    unsigned short* __restrict__ outb, int nN)
{
    constexpr int KQ = K / NS;            // k-slice staged at a time
    constexpr int TXc = M / 4;            // threads per row-group
    constexpr int GROUPS = 512 / TXc;
    constexpr int ROWS = GROUPS * R;      // rows per block
    constexpr int F4 = KQ * M / 4;        // float4s per matrix slice

    __shared__ float ws[2 * KQ * M];      // [0..) = wl slice, [KQ*M..) = wr slice

    const int tid = threadIdx.x;
    const int cq = (tid % TXc) * 4;
    const int g = tid / TXc;
    const int nbase = blockIdx.x * ROWS;
    const int n0 = nbase + g * R;
    const bool full = (nbase + ROWS <= nN);

    const float4 bv = *(const float4*)(bias + cq);
    float4 acc[R];
#pragma unroll
    for (int rr = 0; rr < R; rr++) acc[rr] = bv;

#pragma unroll
    for (int s = 0; s < NS; s++) {
        __syncthreads();                   // previous slice's compute done
        const float4* wlg = (const float4*)(wl + (size_t)s * KQ * M);
        const float4* wrg = (const float4*)(wr + (size_t)s * KQ * M);
        float4* s0 = (float4*)ws;
        float4* s1 = (float4*)(ws + KQ * M);
        for (int i = tid; i < F4; i += 512) {
            s0[i] = wlg[i];
            s1[i] = wrg[i];
        }
        __syncthreads();

        const int kbase = s * KQ;
        if (full) {
            const float* __restrict__ a1p = A1 + (size_t)n0 * K + kbase;
            const float* __restrict__ a2p = A2 + (size_t)n0 * K + kbase;
            for (int kk0 = 0; kk0 < KQ; kk0 += 4) {
                float4 a1v[R], a2v[R];
#pragma unroll
                for (int rr = 0; rr < R; rr++) {
                    a1v[rr] = *(const float4*)(a1p + (size_t)rr * K + kk0);
                    a2v[rr] = *(const float4*)(a2p + (size_t)rr * K + kk0);
                }
                float4 wlv[4], wrv[4];
#pragma unroll
                for (int j = 0; j < 4; j++) {
                    wlv[j] = *(const float4*)(&ws[(kk0 + j) * M + cq]);
                    wrv[j] = *(const float4*)(&ws[KQ * M + (kk0 + j) * M + cq]);
                }
#pragma unroll
                for (int rr = 0; rr < R; rr++) {
                    fma4(acc[rr], a1v[rr].x, wlv[0]);
                    fma4(acc[rr], a1v[rr].y, wlv[1]);
                    fma4(acc[rr], a1v[rr].z, wlv[2]);
                    fma4(acc[rr], a1v[rr].w, wlv[3]);
                    fma4(acc[rr], a2v[rr].x, wrv[0]);
                    fma4(acc[rr], a2v[rr].y, wrv[1]);
                    fma4(acc[rr], a2v[rr].z, wrv[2]);
                    fma4(acc[rr], a2v[rr].w, wrv[3]);
                }
            }
        } else {
            for (int kk0 = 0; kk0 < KQ; kk0 += 4) {
                float4 wlv[4], wrv[4];
#pragma unroll
                for (int j = 0; j < 4; j++) {
                    wlv[j] = *(const float4*)(&ws[(kk0 + j) * M + cq]);
                    wrv[j] = *(const float4*)(&ws[KQ * M + (kk0 + j) * M + cq]);
                }
#pragma unroll
                for (int rr = 0; rr < R; rr++) {
                    int n = n0 + rr;
                    if (n < nN) {
                        float4 a1 = *(const float4*)(A1 + (size_t)n * K + kbase + kk0);
                        float4 a2 = *(const float4*)(A2 + (size_t)n * K + kbase + kk0);
                        fma4(acc[rr], a1.x, wlv[0]);
                        fma4(acc[rr], a1.y, wlv[1]);
                        fma4(acc[rr], a1.z, wlv[2]);
                        fma4(acc[rr], a1.w, wlv[3]);
                        fma4(acc[rr], a2.x, wrv[0]);
                        fma4(acc[rr], a2.y, wrv[1]);
                        fma4(acc[rr], a2.z, wrv[2]);
                        fma4(acc[rr], a2.w, wrv[3]);
                    }
                }
            }
        }
    }

#pragma unroll
    for (int rr = 0; rr < R; rr++) {
        int n = n0 + rr;
        if (n < nN) {
            float4 v = acc[rr];
            v.x = fmaxf(v.x, 0.f); v.y = fmaxf(v.y, 0.f);
            v.z = fmaxf(v.z, 0.f); v.w = fmaxf(v.w, 0.f);
            *(float4*)(out + (size_t)n * M + cq) = v;
            if (outb) {
                ushort4 o;
                o.x = f2bf(v.x); o.y = f2bf(v.y);
                o.z = f2bf(v.z); o.w = f2bf(v.w);
                *(ushort4*)(outb + (size_t)n * M + cq) = o;
            }
        }
    }
}

// ---------------- classifier: [N,32] @ [32,2] + bc ----------------

__global__ void classifier_kernel(const float* __restrict__ h,
                                  const float* __restrict__ wc,
                                  const float* __restrict__ bc,
                                  float* __restrict__ out, int nN) {
    int n = blockIdx.x * blockDim.x + threadIdx.x;
    if (n >= nN) return;
    float a0 = bc[0], a1 = bc[1];
    const float* row = h + (size_t)n * 32;
#pragma unroll
    for (int k = 0; k < 32; k++) {
        float v = row[k];
        a0 = fmaf(v, wc[k * 2 + 0], a0);
        a1 = fmaf(v, wc[k * 2 + 1], a1);
    }
    out[n * 2 + 0] = a0;
    out[n * 2 + 1] = a1;
}

// ---------------- launch ----------------

extern "C" void kernel_launch(void* const* d_in, const int* in_sizes, int n_in,
                              void* d_out, int out_size, void* d_ws, size_t ws_size,
                              hipStream_t stream) {
    const float* x   = (const float*)d_in[0];
    const int*   ei  = (const int*)d_in[1];   // [2,E] int32
    const float* w1l = (const float*)d_in[2];
    const float* b1l = (const float*)d_in[3];
    const float* w1r = (const float*)d_in[4];
    const float* w2l = (const float*)d_in[5];
    const float* b2l = (const float*)d_in[6];
    const float* w2r = (const float*)d_in[7];
    const float* w3l = (const float*)d_in[8];
    const float* b3l = (const float*)d_in[9];
    const float* w3r = (const float*)d_in[10];
    const float* wc  = (const float*)d_in[11];
    const float* bc  = (const float*)d_in[12];
    float* out = (float*)d_out;

    const int N = in_sizes[0] / 128;
    const int E = in_sizes[1] / 2;
    const int NB = (N + 511) / 512;           // scan blocks (<=1024)

    char* p = (char*)d_ws;
    auto alloc = [&](size_t bytes) {
        char* r = p;
        p += (bytes + 511) & ~(size_t)511;
        return r;
    };
    int*   deg    = (int*)  alloc((size_t)N * 4);
    int*   offs   = (int*)  alloc(((size_t)N + 1) * 4);
    int*   cursor = (int*)  alloc((size_t)N * 4);
    float* invd   = (float*)alloc((size_t)N * 4);
    int*   bsum   = (int*)  alloc((size_t)NB * 4);
    int*   csr    = (int*)  alloc((size_t)E * 4);
    float* mean   = (float*)alloc((size_t)N * 128 * 4);
    float* h1     = (float*)alloc((size_t)N * 128 * 4);
    float* h2     = (float*)alloc((size_t)N * 64 * 4);
    float* h3     = (float*)alloc((size_t)N * 32 * 4);
    unsigned short* xb  = (unsigned short*)alloc((size_t)N * 128 * 2);
    unsigned short* h1b = (unsigned short*)alloc((size_t)N * 128 * 2);
    unsigned short* h2b = (unsigned short*)alloc((size_t)N * 64 * 2);

    hipMemsetAsync(deg, 0, (size_t)N * 4, stream);
    hipMemsetAsync(cursor, 0, (size_t)N * 4, stream);

    int eb = (E + 255) / 256;
    degree_kernel<<<eb, 256, 0, stream>>>(ei, deg, E);
    block_sum_kernel<<<NB, 512, 0, stream>>>(deg, bsum, N);
    bsum_scan_kernel<<<1, 1024, 0, stream>>>(bsum, NB);
    scan_write_kernel<<<NB, 512, 0, stream>>>(deg, bsum, offs, invd, N, E);
    fill_kernel<<<eb, 256, 0, stream>>>(ei, offs, cursor, csr, E);

    int n4 = N * 128 / 4;
    f32_to_bf16_kernel<<<(n4 + 255) / 256, 256, 0, stream>>>(x, xb, n4);

    int ab = (N + 3) / 4;

    // rows per block = (512/(M/4)) * R = 8192/M (R=4)
    int g1 = (N + 8192 / 128 - 1) / (8192 / 128);   // 64 rows/blk  -> 1563
    int g2 = (N + 8192 / 64  - 1) / (8192 / 64);    // 128 rows/blk -> 782
    int g3 = (N + 8192 / 32  - 1) / (8192 / 32);    // 256 rows/blk -> 391

    aggregate_bf16_kernel<128><<<ab, 256, 0, stream>>>(xb, offs, csr, invd, mean, N);
    gemm_relu_ldsw<128, 128, 4, 4><<<g1, 512, 0, stream>>>(mean, x, w1l, w1r, b1l, h1, h1b, N);

    aggregate_bf16_kernel<128><<<ab, 256, 0, stream>>>(h1b, offs, csr, invd, mean, N);
    gemm_relu_ldsw<128, 64, 4, 4><<<g2, 512, 0, stream>>>(mean, h1, w2l, w2r, b2l, h2, h2b, N);

    aggregate_bf16_kernel<64><<<ab, 256, 0, stream>>>(h2b, offs, csr, invd, mean, N);
    gemm_relu_ldsw<64, 32, 4, 2><<<g3, 512, 0, stream>>>(mean, h2, w3l, w3r, b3l, h3, nullptr, N);

    classifier_kernel<<<(N + 255) / 256, 256, 0, stream>>>(h3, wc, bc, out, N);
}